// Round 1
// 3093.276 us; speedup vs baseline: 2.9904x; 2.9904x over previous
//
#include <hip/hip_runtime.h>
#include <hip/hip_bf16.h>

// ---- model constants ----
#define BB 16
#define TT 256
#define SS 256
#define N_AST 300
#define DD 512
#define HH 8
#define DKK 64
#define DFF 2048
#define LL 6

typedef __attribute__((ext_vector_type(8))) short short8;
typedef __attribute__((ext_vector_type(4))) float f32x4;
typedef __hip_bfloat16 bf16;

// async global->LDS, 16B per lane. LDS dest must be wave-uniform base; data
// lands at base + lane*16. Global SOURCE is per-lane (m173: pre-swizzle it).
__device__ __forceinline__ void llds16(const void* g, void* l) {
    __builtin_amdgcn_global_load_lds(
        (const __attribute__((address_space(1))) void*)(uintptr_t)g,
        (__attribute__((address_space(3))) void*)(uint32_t)(uintptr_t)l,
        16, 0, 0);
}

__device__ __forceinline__ unsigned int pk2(float a, float b) {
    bf16 x = __float2bfloat16(a), y = __float2bfloat16(b);
    unsigned short ux = *(unsigned short*)&x, uy = *(unsigned short*)&y;
    return (unsigned int)ux | ((unsigned int)uy << 16);
}

// =========================================================================
// weight transpose + fp32->bf16: dst[C,R] = bf16(src[R,C]^T). blockIdx.z = mat.
// =========================================================================
__global__ __launch_bounds__(256) void transp_k(const float* __restrict__ src,
                                                bf16* __restrict__ dst,
                                                int R, int C) {
    __shared__ float ts[32][33];
    size_t mstride = (size_t)R * C;
    src += blockIdx.z * mstride;
    dst += blockIdx.z * mstride;
    int r0 = blockIdx.y * 32, c0 = blockIdx.x * 32;
    int tx = threadIdx.x & 31, ty = threadIdx.x >> 5;   // ty: 0..7
    #pragma unroll
    for (int p = 0; p < 4; p++)
        ts[ty + p * 8][tx] = src[(size_t)(r0 + ty + p * 8) * C + c0 + tx];
    __syncthreads();
    #pragma unroll
    for (int p = 0; p < 4; p++) {
        int rt = ty + p * 8;
        dst[(size_t)(c0 + rt) * R + r0 + tx] = __float2bfloat16(ts[tx][rt]);
    }
}

// flat fp32 -> bf16 (n multiple of 1024)
__global__ __launch_bounds__(256) void cvt_k(const float* __restrict__ src,
                                             bf16* __restrict__ dst) {
    int i = (blockIdx.x * 256 + threadIdx.x) * 4;
    #pragma unroll
    for (int j = 0; j < 4; j++) dst[i + j] = __float2bfloat16(src[i + j]);
}

// src_embed [4096,512] -> Acat[:, 0:512] bf16 (Acat row stride 1024)
__global__ __launch_bounds__(256) void cat_src_k(const float* __restrict__ src,
                                                 bf16* __restrict__ acat) {
    int row = blockIdx.x;
    int d0 = threadIdx.x, d1 = threadIdx.x + 256;
    acat[(size_t)row * 1024 + d0] = __float2bfloat16(src[(size_t)row * DD + d0]);
    acat[(size_t)row * 1024 + d1] = __float2bfloat16(src[(size_t)row * DD + d1]);
}

// =========================================================================
// Embedding + positional encoding; writes fp32 (residual) + bf16 (GEMM A)
// =========================================================================
__global__ __launch_bounds__(256) void embed_k(const int* __restrict__ ids,
                                               const float* __restrict__ emb,
                                               float* __restrict__ x,
                                               bf16* __restrict__ x16) {
    int row = blockIdx.x;
    int t = row & (TT - 1);
    int id = ids[row];
    int d0 = threadIdx.x, d1 = threadIdx.x + 256;
    float e0 = emb[(size_t)id * DD + d0];
    float e1 = emb[(size_t)id * DD + d1];
    const float c = -9.210340371976184f / 512.0f;
    float f0 = expf((float)(d0 & ~1) * c);
    float f1 = expf((float)(d1 & ~1) * c);
    float p0 = (d0 & 1) ? cosf(t * f0) : sinf(t * f0);
    float p1 = (d1 & 1) ? cosf(t * f1) : sinf(t * f1);
    size_t o = (size_t)row * DD;
    float v0 = e0 + p0, v1 = e1 + p1;
    x[o + d0] = v0; x[o + d1] = v1;
    x16[o + d0] = __float2bfloat16(v0);
    x16[o + d1] = __float2bfloat16(v1);
}

// =========================================================================
// conv over node axis: ast1 fp32 (for mm_attn), ast_e1 bf16 -> Acat[:,512:]
// =========================================================================
__global__ __launch_bounds__(256) void conv_k(const float* __restrict__ ast_out,
                                              const float* __restrict__ ast_emb,
                                              const float* __restrict__ cw,
                                              const float* __restrict__ cb,
                                              float* __restrict__ ast1,
                                              bf16* __restrict__ acat) {
    int s = blockIdx.x, b = blockIdx.y;
    __shared__ float w[N_AST];
    for (int i = threadIdx.x; i < N_AST; i += 256) w[i] = cw[s * N_AST + i];
    __syncthreads();
    int d0 = threadIdx.x, d1 = threadIdx.x + 256;
    float a0 = 0, a1 = 0, e0 = 0, e1 = 0;
    const float* po = ast_out + (size_t)b * N_AST * DD;
    const float* pm = ast_emb + (size_t)b * N_AST * DD;
    for (int n = 0; n < N_AST; n++) {
        float wn = w[n];
        a0 += wn * po[n * DD + d0];
        a1 += wn * po[n * DD + d1];
        e0 += wn * pm[n * DD + d0];
        e1 += wn * pm[n * DD + d1];
    }
    float bbv = cb[s];
    size_t row = (size_t)b * SS + s;
    ast1[row * DD + d0] = a0 + bbv;
    ast1[row * DD + d1] = a1 + bbv;
    acat[row * 1024 + 512 + d0] = __float2bfloat16(e0 + bbv);
    acat[row * 1024 + 512 + d1] = __float2bfloat16(e1 + bbv);
}

// =========================================================================
// mm attention (fp32): softmax over t of ast1 . enc / 8, then ctx
// =========================================================================
__global__ __launch_bounds__(256) void mm_attn_k(const float* __restrict__ ast1,
                                                 const float* __restrict__ enc,
                                                 float* __restrict__ mm_ctx) {
    int s = blockIdx.x, b = blockIdx.y;
    __shared__ float arow[DD];
    __shared__ float red[256];
    __shared__ float p[256];
    size_t abase = ((size_t)b * SS + s) * DD;
    arow[threadIdx.x] = ast1[abase + threadIdx.x];
    arow[threadIdx.x + 256] = ast1[abase + threadIdx.x + 256];
    __syncthreads();
    int t = threadIdx.x;
    const float* erow = enc + ((size_t)b * TT + t) * DD;
    float acc = 0;
    #pragma unroll 8
    for (int k = 0; k < DD; k++) acc += arow[k] * erow[k];
    acc *= 0.125f;
    red[t] = acc; __syncthreads();
    for (int off = 128; off > 0; off >>= 1) {
        if (t < off) red[t] = fmaxf(red[t], red[t + off]);
        __syncthreads();
    }
    float mx = red[0]; __syncthreads();
    float e = __expf(acc - mx);
    red[t] = e; __syncthreads();
    for (int off = 128; off > 0; off >>= 1) {
        if (t < off) red[t] += red[t + off];
        __syncthreads();
    }
    p[t] = e / red[0];
    __syncthreads();
    float c0 = 0, c1 = 0;
    int d0 = threadIdx.x, d1 = threadIdx.x + 256;
    for (int tt = 0; tt < 256; tt++) {
        float pv = p[tt];
        const float* er = enc + ((size_t)b * TT + tt) * DD;
        c0 += pv * er[d0];
        c1 += pv * er[d1];
    }
    size_t o = ((size_t)b * SS + s) * DD;
    mm_ctx[o + d0] = c0;
    mm_ctx[o + d1] = c1;
}

// =========================================================================
// MFMA bf16 GEMM: C[M,N] = A[M,K](bf16, lda) @ Bt[N,K](bf16)^T
// tile 128x64, BK=32, 256 thr (4 waves in 2x2), 16x16x32 MFMA.
// epilogue: +bias, +res(fp32,[M,N]), relu, write Cf(fp32) and/or Ch(bf16).
// =========================================================================
__global__ __launch_bounds__(256) void gemm_bf16_k(const bf16* __restrict__ A,
                                                   const bf16* __restrict__ Bt,
                                                   const float* __restrict__ bias,
                                                   const float* __restrict__ res,
                                                   float* __restrict__ Cf,
                                                   bf16* __restrict__ Ch,
                                                   int M, int N, int K, int lda,
                                                   int relu) {
    __shared__ __align__(16) short Als[128 * 32];   // [m][k] bf16
    __shared__ __align__(16) short Bls[64 * 32];    // [n][k] bf16
    int tid = threadIdx.x;
    int w = tid >> 6, l = tid & 63;
    int wm = w >> 1, wn = w & 1;
    int m0 = blockIdx.y * 128, n0 = blockIdx.x * 64;
    const short* Ag = (const short*)A;
    const short* Bg = (const short*)Bt;

    f32x4 zero = {0.f, 0.f, 0.f, 0.f};
    f32x4 acc[4][2];
    #pragma unroll
    for (int mt = 0; mt < 4; mt++)
        #pragma unroll
        for (int nt = 0; nt < 2; nt++) acc[mt][nt] = zero;

    int lm = l & 15, lq = l >> 4;   // fragment row/col and k-quad

    for (int k0 = 0; k0 < K; k0 += 32) {
        // stage A tile 128x32 (8 KB): 2 issues x 256 lanes x 16 B
        #pragma unroll
        for (int i = 0; i < 2; i++) {
            int e = i * 256 + tid;
            const short* g = Ag + (size_t)(m0 + (e >> 2)) * lda + k0 + (e & 3) * 8;
            llds16(g, (char*)Als + (size_t)(i * 256 + w * 64) * 16);
        }
        // stage B tile 64x32 (4 KB): 1 issue
        {
            int e = tid;
            const short* g = Bg + (size_t)(n0 + (e >> 2)) * K + k0 + (e & 3) * 8;
            llds16(g, (char*)Bls + (size_t)(w * 64) * 16);
        }
        __syncthreads();
        short8 af[4], bfr[2];
        #pragma unroll
        for (int mt = 0; mt < 4; mt++)
            af[mt] = *(const short8*)&Als[(wm * 64 + mt * 16 + lm) * 32 + lq * 8];
        #pragma unroll
        for (int nt = 0; nt < 2; nt++)
            bfr[nt] = *(const short8*)&Bls[(wn * 32 + nt * 16 + lm) * 32 + lq * 8];
        #pragma unroll
        for (int mt = 0; mt < 4; mt++)
            #pragma unroll
            for (int nt = 0; nt < 2; nt++)
                acc[mt][nt] = __builtin_amdgcn_mfma_f32_16x16x32_bf16(
                    af[mt], bfr[nt], acc[mt][nt], 0, 0, 0);
        __syncthreads();
    }

    // epilogue: C/D layout col = l&15, row = (l>>4)*4 + r
    #pragma unroll
    for (int mt = 0; mt < 4; mt++) {
        #pragma unroll
        for (int nt = 0; nt < 2; nt++) {
            int col = n0 + wn * 32 + nt * 16 + lm;
            int rowb = m0 + wm * 64 + mt * 16 + lq * 4;
            float bv = bias ? bias[col] : 0.f;
            #pragma unroll
            for (int r = 0; r < 4; r++) {
                int row = rowb + r;
                float v = acc[mt][nt][r] + bv;
                if (res)  v += res[(size_t)row * N + col];
                if (relu) v = fmaxf(v, 0.f);
                if (Cf) Cf[(size_t)row * N + col] = v;
                if (Ch) Ch[(size_t)row * N + col] = __float2bfloat16(v);
            }
        }
    }
}

// =========================================================================
// Fused attention: per block = (64 q-rows, head, batch). keys = 256 always.
//   scores S^T = K @ Q^T via MFMA (swapped operands -> row-softmax is
//   per-lane + 2 shfl_xor), mask, softmax, probs fp32 coalesced out,
//   ctx = P @ V via MFMA, ctx bf16 out.
// LDS: KP 32KB (K bf16 [256][64] XOR-swizzled; reused as P^T bf16 [64][256]
//      XOR-swizzled), VB 32KB (V bf16 [256][64] linear). 65KB -> 2 blocks/CU.
// mode: 0 self (pad|causal), 1 enc (pad), 2 none.
// =========================================================================
__global__ __launch_bounds__(256) void attn_fused_k(
        const bf16* __restrict__ qp, int qs,
        const bf16* __restrict__ kp, int kss,
        const bf16* __restrict__ vp, int vs,
        const int* __restrict__ ids, float* __restrict__ probs,
        bf16* __restrict__ ctx16, int mode) {
    __shared__ __align__(16) char KP[256 * 128];
    __shared__ __align__(16) char VB[256 * 128];
    __shared__ unsigned long long mbits[4];

    int tid = threadIdx.x;
    int w = tid >> 6, lane = tid & 63;
    int lm = lane & 15, lq = lane >> 4;
    int t0 = blockIdx.x * 64;
    int h = blockIdx.y, b = blockIdx.z;
    size_t brow = (size_t)b * 256;
    int hcol = h * DKK;

    // ---- stage K (swizzled via pre-swizzled global src) + V (linear) ----
    #pragma unroll
    for (int p = 0; p < 8; p++) {
        int L = p * 256 + tid;
        int s = L >> 3;
        int cK = (L & 7) ^ (s & 7);   // inverse swizzle on the SOURCE
        llds16(kp + (brow + s) * (size_t)kss + hcol + cK * 8,
               KP + (size_t)(p * 256 + w * 64) * 16);
        llds16(vp + (brow + s) * (size_t)vs + hcol + (L & 7) * 8,
               VB + (size_t)(p * 256 + w * 64) * 16);
    }
    // pad-key bitmask: one ballot per wave (s = w*64 + lane)
    int idv = (mode != 2) ? ids[(size_t)b * 256 + tid] : 1;
    unsigned long long bm = __ballot(idv == 0);
    if (lane == 0) mbits[w] = bm;

    // Q fragments in registers (B-operand: n = t = w*16+lm, k = dk)
    int tg = t0 + w * 16 + lm;
    const short* qrow = (const short*)(qp + (brow + tg) * (size_t)qs + hcol);
    short8 qf0 = *(const short8*)(qrow + lq * 8);
    short8 qf1 = *(const short8*)(qrow + 32 + lq * 8);
    __syncthreads();

    unsigned long long mb[4] = {mbits[0], mbits[1], mbits[2], mbits[3]};
    int causal = (mode == 0);

    // ---- scores: S^T tile, m = s (16 tiles), n = wave's 16 t-cols ----
    f32x4 sa[16];
    #pragma unroll
    for (int mt = 0; mt < 16; mt++) {
        f32x4 z = {0.f, 0.f, 0.f, 0.f};
        int srow = mt * 16 + lm;
        int c0 = lq ^ (lm & 7);
        int c1 = (4 + lq) ^ (lm & 7);
        short8 kf0 = *(const short8*)(KP + srow * 128 + c0 * 16);
        short8 kf1 = *(const short8*)(KP + srow * 128 + c1 * 16);
        z = __builtin_amdgcn_mfma_f32_16x16x32_bf16(kf0, qf0, z, 0, 0, 0);
        z = __builtin_amdgcn_mfma_f32_16x16x32_bf16(kf1, qf1, z, 0, 0, 0);
        sa[mt] = z;
    }

    // ---- mask + scale + row-softmax (per lane over 64 s, then 2 shfls) ----
    float mloc = -3.4e38f;
    #pragma unroll
    for (int mt = 0; mt < 16; mt++) {
        #pragma unroll
        for (int r = 0; r < 4; r++) {
            int s = mt * 16 + lq * 4 + r;
            int bit = (int)((mb[mt >> 2] >> ((mt & 3) * 16 + lq * 4 + r)) & 1ull);
            bool msk = bit || (causal && (s > tg));
            float v = msk ? -1e9f : sa[mt][r] * 0.125f;
            sa[mt][r] = v;
            mloc = fmaxf(mloc, v);
        }
    }
    mloc = fmaxf(mloc, __shfl_xor(mloc, 16));
    mloc = fmaxf(mloc, __shfl_xor(mloc, 32));
    float ssum = 0.f;
    #pragma unroll
    for (int mt = 0; mt < 16; mt++)
        #pragma unroll
        for (int r = 0; r < 4; r++) {
            float e = __expf(sa[mt][r] - mloc);
            sa[mt][r] = e;
            ssum += e;
        }
    ssum += __shfl_xor(ssum, 16);
    ssum += __shfl_xor(ssum, 32);
    float inv = 1.f / ssum;

    // ---- all waves done reading K: overwrite region with P^T (swizzled) ----
    __syncthreads();
    int trow = w * 16 + lm;
    #pragma unroll
    for (int mt = 0; mt < 16; mt++) {
        unsigned int d0 = pk2(sa[mt][0] * inv, sa[mt][1] * inv);
        unsigned int d1 = pk2(sa[mt][2] * inv, sa[mt][3] * inv);
        int byte = (trow * 512 + mt * 32 + lq * 8) ^ ((trow & 7) << 4);
        *(uint2*)(KP + byte) = make_uint2(d0, d1);
    }

    // ---- probs fp32, coalesced; each wave writes its own 16 rows ----
    size_t pb = (((size_t)b * HH + h) * TT + t0) * 256;
    #pragma unroll
    for (int tr = 0; tr < 16; tr++) {
        int t = w * 16 + tr;
        int byte = (t * 512 + lane * 8) ^ ((t & 7) << 4);
        uint2 pv = *(const uint2*)(KP + byte);
        float4 o;
        o.x = __uint_as_float(pv.x << 16);
        o.y = __uint_as_float(pv.x & 0xffff0000u);
        o.z = __uint_as_float(pv.y << 16);
        o.w = __uint_as_float(pv.y & 0xffff0000u);
        *(float4*)(probs + pb + (size_t)t * 256 + lane * 4) = o;
    }

    // ---- PV: ctx[t, dk] = P @ V ----
    f32x4 ca[4];
    #pragma unroll
    for (int nt = 0; nt < 4; nt++) ca[nt] = (f32x4){0.f, 0.f, 0.f, 0.f};
    const short* Vp = (const short*)VB;
    #pragma unroll
    for (int ks = 0; ks < 8; ks++) {
        int sb = ks * 32 + lq * 8;
        int ab = (trow * 512 + sb * 2) ^ ((trow & 7) << 4);
        short8 pa = *(const short8*)(KP + ab);
        #pragma unroll
        for (int nt = 0; nt < 4; nt++) {
            int dk = nt * 16 + lm;
            short8 vbf;
            #pragma unroll
            for (int j = 0; j < 8; j++) vbf[j] = Vp[(sb + j) * 64 + dk];
            ca[nt] = __builtin_amdgcn_mfma_f32_16x16x32_bf16(pa, vbf, ca[nt], 0, 0, 0);
        }
    }
    #pragma unroll
    for (int nt = 0; nt < 4; nt++) {
        #pragma unroll
        for (int r = 0; r < 4; r++) {
            int t = t0 + w * 16 + lq * 4 + r;
            ctx16[(brow + t) * DD + hcol + nt * 16 + lm] = __float2bfloat16(ca[nt][r]);
        }
    }
}

// =========================================================================
// LayerNorm (biased var, eps 1e-5); writes fp32 + optional bf16
// =========================================================================
__global__ __launch_bounds__(256) void ln_k(const float* __restrict__ in,
                                            const float* __restrict__ g,
                                            const float* __restrict__ bt,
                                            float* __restrict__ out,
                                            bf16* __restrict__ out16) {
    int row = blockIdx.x;
    const float* x = in + (size_t)row * DD;
    int i0 = threadIdx.x, i1 = threadIdx.x + 256;
    float v0 = x[i0], v1 = x[i1];
    __shared__ float red[256];
    red[i0] = v0 + v1; __syncthreads();
    for (int off = 128; off > 0; off >>= 1) {
        if (i0 < off) red[i0] += red[i0 + off];
        __syncthreads();
    }
    float mu = red[0] * (1.0f / DD); __syncthreads();
    float d0 = v0 - mu, d1 = v1 - mu;
    red[i0] = d0 * d0 + d1 * d1; __syncthreads();
    for (int off = 128; off > 0; off >>= 1) {
        if (i0 < off) red[i0] += red[i0 + off];
        __syncthreads();
    }
    float rstd = rsqrtf(red[0] * (1.0f / DD) + 1e-5f);
    float g0 = g ? g[i0] : 1.f, g1 = g ? g[i1] : 1.f;
    float b0 = bt ? bt[i0] : 0.f, b1 = bt ? bt[i1] : 0.f;
    size_t o = (size_t)row * DD;
    float r0 = d0 * rstd * g0 + b0, r1 = d1 * rstd * g1 + b1;
    out[o + i0] = r0; out[o + i1] = r1;
    if (out16) {
        out16[o + i0] = __float2bfloat16(r0);
        out16[o + i1] = __float2bfloat16(r1);
    }
}

// =========================================================================
// host orchestration
// =========================================================================
static inline void g_launch(const bf16* A, const bf16* Bt, const float* bias,
                            const float* res, float* Cf, bf16* Ch,
                            int M, int N, int K, int lda, int relu,
                            hipStream_t stream) {
    gemm_bf16_k<<<dim3(N / 64, M / 128), 256, 0, stream>>>(A, Bt, bias, res, Cf, Ch,
                                                           M, N, K, lda, relu);
}

extern "C" void kernel_launch(void* const* d_in, const int* in_sizes, int n_in,
                              void* d_out, int out_size, void* d_ws, size_t ws_size,
                              hipStream_t stream) {
    const int*   dec_inputs  = (const int*)  d_in[0];
    const int*   enc_inputs  = (const int*)  d_in[1];
    const float* enc_outputs = (const float*)d_in[2];
    const float* ast_outputs = (const float*)d_in[3];
    const float* src_embed   = (const float*)d_in[4];
    const float* ast_embed   = (const float*)d_in[5];
    const float* emb         = (const float*)d_in[7];
    const float* attn_W      = (const float*)d_in[8];
    const float* attn_ln_g   = (const float*)d_in[9];
    const float* attn_ln_b   = (const float*)d_in[10];
    const float* ffn_W1      = (const float*)d_in[11];
    const float* ffn_W2      = (const float*)d_in[12];
    const float* conv_w      = (const float*)d_in[13];
    const float* conv_b      = (const float*)d_in[14];
    const float* multi_ffn_W = (const float*)d_in[15];
    const float* multi_ffn_b = (const float*)d_in[16];

    const size_t NTD = (size_t)BB * TT * DD;        // 2,097,152
    const size_t ATT = (size_t)BB * HH * TT * 256;  // 8,388,608

    float* out_x    = (float*)d_out;
    float* out_self = out_x + NTD;
    float* out_enc  = out_self + (size_t)LL * ATT;
    float* out_ast  = out_enc + (size_t)LL * ATT;

    // ---- workspace bump allocator (256B aligned) ----
    char* wp = (char*)d_ws;
    auto alloc = [&](size_t bytes) { char* r = wp; wp += (bytes + 255) & ~(size_t)255; return (void*)r; };
    float* xb    = (float*)alloc(NTD * 4);
    float* tmp   = (float*)alloc(NTD * 4);
    float* ast1  = (float*)alloc(NTD * 4);
    float* mmctx = (float*)alloc(NTD * 4);
    bf16* xb16   = (bf16*)alloc(NTD * 2);
    bf16* enc16  = (bf16*)alloc(NTD * 2);
    bf16* mo16   = (bf16*)alloc(NTD * 2);
    bf16* cb16   = (bf16*)alloc(NTD * 2);
    bf16* hb16   = (bf16*)alloc((size_t)BB * TT * DFF * 2);
    bf16* acat   = (bf16*)alloc(NTD * 2 * 2);                        // [4096,1024]
    bf16* qkv16  = (bf16*)alloc((size_t)BB * TT * 3 * DD * 2);       // [4096,1536]
    bf16* q16x   = (bf16*)alloc(NTD * 2);                            // [4096,512]
    bf16* kv16   = (bf16*)alloc((size_t)BB * TT * 2 * DD * 2);       // [4096,1024]
    bf16* Wt_attn  = (bf16*)alloc((size_t)72 * DD * DD * 2);
    bf16* Wt_ffn1  = (bf16*)alloc((size_t)LL * DD * DFF * 2);        // [2048,512] x6
    bf16* Wt_ffn2  = (bf16*)alloc((size_t)LL * DFF * DD * 2);        // [512,2048] x6
    bf16* Wt_multi = (bf16*)alloc((size_t)2 * DD * DD * 2);          // [512,1024]

    const int M = BB * TT;  // 4096

    // ---- one-time (per call) weight transposes + input converts ----
    transp_k<<<dim3(16, 16, 72), 256, 0, stream>>>(attn_W, Wt_attn, DD, DD);
    transp_k<<<dim3(64, 16, LL), 256, 0, stream>>>(ffn_W1, Wt_ffn1, DD, DFF);
    transp_k<<<dim3(16, 64, LL), 256, 0, stream>>>(ffn_W2, Wt_ffn2, DFF, DD);
    transp_k<<<dim3(16, 32, 1), 256, 0, stream>>>(multi_ffn_W, Wt_multi, 2 * DD, DD);
    cvt_k<<<NTD / 1024, 256, 0, stream>>>(enc_outputs, enc16);
    cat_src_k<<<M, 256, 0, stream>>>(src_embed, acat);

    // ---- embedding + PE ----
    embed_k<<<M, 256, 0, stream>>>(dec_inputs, emb, xb, xb16);

    // ---- Multi_model front-end ----
    conv_k<<<dim3(SS, BB), 256, 0, stream>>>(ast_outputs, ast_embed, conv_w, conv_b,
                                             ast1, acat);
    mm_attn_k<<<dim3(SS, BB), 256, 0, stream>>>(ast1, enc_outputs, mmctx);
    // multi_out = cat(src,ast_e1) @ multi_ffn_W + b + mm_ctx  (bf16 out only)
    g_launch(acat, Wt_multi, multi_ffn_b, mmctx, nullptr, mo16,
             M, DD, 2 * DD, 2 * DD, 0, stream);

    // ---- decoder layers ----
    for (int l = 0; l < LL; l++) {
        for (int a = 0; a < 3; a++) {
            const bf16* Wbase = Wt_attn + (size_t)((l * 3 + a) * 4) * DD * DD;
            const bf16* Wq = Wbase;                         // rows 0..511 of fused B^T
            const bf16* Wk = Wbase + (size_t)DD * DD;       // Wk^T,Wv^T contiguous
            const bf16* Wo = Wbase + (size_t)3 * DD * DD;
            const float* g  = attn_ln_g + ((size_t)l * 3 + a) * DD;
            const float* be = attn_ln_b + ((size_t)l * 3 + a) * DD;
            float* probs = ((a == 0) ? out_self : (a == 1) ? out_enc : out_ast) + (size_t)l * ATT;

            if (a == 0) {
                // fused QKV projection: Bt = [Wq^T;Wk^T;Wv^T] (contiguous), N=1536
                g_launch(xb16, Wq, nullptr, nullptr, nullptr, qkv16,
                         M, 3 * DD, DD, DD, 0, stream);
                attn_fused_k<<<dim3(TT / 64, HH, BB), 256, 0, stream>>>(
                    qkv16, 3 * DD, qkv16 + DD, 3 * DD, qkv16 + 2 * DD, 3 * DD,
                    dec_inputs, probs, cb16, 0);
            } else {
                const bf16* kvsrc = (a == 1) ? enc16 : mo16;
                g_launch(xb16, Wq, nullptr, nullptr, nullptr, q16x,
                         M, DD, DD, DD, 0, stream);
                // fused KV projection: Bt = [Wk^T;Wv^T] (contiguous), N=1024
                g_launch(kvsrc, Wk, nullptr, nullptr, nullptr, kv16,
                         M, 2 * DD, DD, DD, 0, stream);
                attn_fused_k<<<dim3(TT / 64, HH, BB), 256, 0, stream>>>(
                    q16x, DD, kv16, 2 * DD, kv16 + DD, 2 * DD,
                    (a == 1) ? enc_inputs : nullptr, probs, cb16, (a == 1) ? 1 : 2);
            }
            g_launch(cb16, Wo, nullptr, xb, tmp, nullptr, M, DD, DD, DD, 0, stream);
            ln_k<<<M, 256, 0, stream>>>(tmp, g, be, xb, xb16);
        }
        // FFN
        g_launch(xb16, Wt_ffn1 + (size_t)l * DD * DFF, nullptr, nullptr,
                 nullptr, hb16, M, DFF, DD, DD, 1 /*relu*/, stream);
        g_launch(hb16, Wt_ffn2 + (size_t)l * DFF * DD, nullptr, xb,
                 tmp, nullptr, M, DD, DFF, DFF, 0, stream);
        float* xdst = (l == LL - 1) ? out_x : xb;
        ln_k<<<M, 256, 0, stream>>>(tmp, nullptr, nullptr, xdst,
                                    (l == LL - 1) ? nullptr : xb16);
    }
}